// Round 1
// baseline (497.680 us; speedup 1.0000x reference)
//
#include <hip/hip_runtime.h>
#include <stdint.h>

// ---------------------------------------------------------------------------
// MHA w/ RoPE, causal.  B=4 S=2048 D=1024 H=16 dk=64.
// Pipeline: cast->bf16, QKV GEMM (C=A*B^T, V stored transposed), RoPE(Q,K),
// flash attention (online softmax), out-proj GEMM -> fp32.
// ---------------------------------------------------------------------------

typedef __attribute__((ext_vector_type(8))) __bf16 bf16x8;
typedef __attribute__((ext_vector_type(4))) float f32x4;

typedef __attribute__((address_space(1))) uint32_t AS1u32;
typedef __attribute__((address_space(3))) uint32_t AS3u32;

__device__ __forceinline__ unsigned short f2bf(float f) {
  uint32_t u = __builtin_bit_cast(uint32_t, f);
  u += 0x7fffu + ((u >> 16) & 1u);              // RNE
  return (unsigned short)(u >> 16);
}
__device__ __forceinline__ float bf2f(unsigned short h) {
  return __builtin_bit_cast(float, (uint32_t)h << 16);
}
__device__ __forceinline__ void lds_load16(const void* g, void* l) {
  // async global->LDS, 16B/lane; LDS dest must be wave-uniform base + lane*16
  __builtin_amdgcn_global_load_lds((AS1u32*)g, (AS3u32*)l, 16, 0, 0);
}
__device__ __forceinline__ f32x4 mfma16(bf16x8 a, bf16x8 b, f32x4 c) {
  return __builtin_amdgcn_mfma_f32_16x16x32_bf16(a, b, c, 0, 0, 0);
}

// ---- elementwise ----------------------------------------------------------
__global__ void cast_f32_to_bf16x4(const float4* __restrict__ in,
                                   uint2* __restrict__ out, int n4) {
  int i = blockIdx.x * 256 + threadIdx.x;
  if (i >= n4) return;
  float4 v = in[i];
  uint2 o;
  o.x = (uint32_t)f2bf(v.x) | ((uint32_t)f2bf(v.y) << 16);
  o.y = (uint32_t)f2bf(v.z) | ((uint32_t)f2bf(v.w) << 16);
  out[i] = o;
}

__global__ void rope_table_kernel(float* __restrict__ tab) {
  int i = blockIdx.x * 256 + threadIdx.x;     // 2048*32 exact
  int s = i >> 5, p = i & 31;
  double ang = (double)s * pow(10000.0, -(double)p / 32.0);
  tab[2 * i]     = (float)cos(ang);
  tab[2 * i + 1] = (float)sin(ang);
}

__global__ void rope_apply_kernel(unsigned short* __restrict__ buf,
                                  const float2* __restrict__ tab) {
  int i = blockIdx.x * 256 + threadIdx.x;     // pair idx, 8192*512 exact
  int row = i >> 9;                           // token row in [0,8192)
  int pp  = i & 511;                          // pair within row
  float2 cs = tab[(row & 2047) * 32 + (pp & 31)];
  uint32_t v = *(uint32_t*)(buf + 2 * (size_t)i);
  float x0 = bf2f((unsigned short)(v & 0xffffu));
  float x1 = bf2f((unsigned short)(v >> 16));
  float o0 = cs.x * x0 - cs.y * x1;
  float o1 = cs.y * x0 + cs.x * x1;
  *(uint32_t*)(buf + 2 * (size_t)i) =
      (uint32_t)f2bf(o0) | ((uint32_t)f2bf(o1) << 16);
}

// ---- GEMM: C[M][N] = A[M][K] * B[N][K]^T, bf16 in, fp32 acc ---------------
// MODE 0: N=3072 fused QKV epilogue (Q,K row-major bf16; V transposed to Vt)
// MODE 1: fp32 output buffer
template <int MODE>
__global__ __launch_bounds__(256)
void gemm_bt(const unsigned short* __restrict__ A,
             const unsigned short* __restrict__ B,
             unsigned short* __restrict__ Qo,
             unsigned short* __restrict__ Ko,
             unsigned short* __restrict__ Vt,
             float* __restrict__ CF,
             int M, int N, int K) {
  __shared__ unsigned short As[128 * 64];
  __shared__ unsigned short Bs[128 * 64];
  const int tid = threadIdx.x;
  const int lane = tid & 63, wave = tid >> 6;
  const int l16 = lane & 15, g4 = lane >> 4;
  const int wr = wave >> 1, wc = wave & 1;   // 2x2 waves, 64x64 each
  const int row0 = blockIdx.y * 128;
  const int col0 = blockIdx.x * 128;

  const f32x4 fz = {0.f, 0.f, 0.f, 0.f};
  f32x4 acc[4][4];
#pragma unroll
  for (int m = 0; m < 4; ++m)
#pragma unroll
    for (int n = 0; n < 4; ++n) acc[m][n] = fz;

  for (int kt = 0; kt < K; kt += 64) {
    __syncthreads();
#pragma unroll
    for (int i = 0; i < 4; ++i) {
      int flat = i * 2048 + tid * 8;          // bf16 element index in tile
      int r = flat >> 6, c = flat & 63;
      lds_load16(A + (size_t)(row0 + r) * K + kt + c, &As[flat]);
      lds_load16(B + (size_t)(col0 + r) * K + kt + c, &Bs[flat]);
    }
    __syncthreads();
#pragma unroll
    for (int kk = 0; kk < 2; ++kk) {
      bf16x8 af[4], bfr[4];
#pragma unroll
      for (int m = 0; m < 4; ++m)
        af[m] = *(const bf16x8*)&As[(wr * 64 + m * 16 + l16) * 64 + kk * 32 + g4 * 8];
#pragma unroll
      for (int n = 0; n < 4; ++n)
        bfr[n] = *(const bf16x8*)&Bs[(wc * 64 + n * 16 + l16) * 64 + kk * 32 + g4 * 8];
#pragma unroll
      for (int m = 0; m < 4; ++m)
#pragma unroll
        for (int n = 0; n < 4; ++n)
          acc[m][n] = mfma16(af[m], bfr[n], acc[m][n]);
    }
  }

  // C/D layout: row = g4*4 + r, col = l16  [m89-verified]
  const int rbase = row0 + wr * 64 + g4 * 4;
  const int cbase = col0 + wc * 64 + l16;
  if (MODE == 1) {
#pragma unroll
    for (int m = 0; m < 4; ++m)
#pragma unroll
      for (int n = 0; n < 4; ++n)
#pragma unroll
        for (int r = 0; r < 4; ++r)
          CF[(size_t)(rbase + m * 16 + r) * N + cbase + n * 16] = acc[m][n][r];
  } else {
    const int seg = col0 >> 10;               // 0=Q 1=K 2=V (tiles never straddle)
    if (seg < 2) {
      unsigned short* O = seg ? Ko : Qo;
      const int cl = cbase - (seg << 10);
#pragma unroll
      for (int m = 0; m < 4; ++m)
#pragma unroll
        for (int n = 0; n < 4; ++n)
#pragma unroll
          for (int r = 0; r < 4; ++r)
            O[(size_t)(rbase + m * 16 + r) * 1024 + cl + n * 16] = f2bf(acc[m][n][r]);
    } else {
      // V: write transposed Vt[bh][d][s]; 4 acc rows = 4 consecutive s -> ushort4
#pragma unroll
      for (int m = 0; m < 4; ++m) {
        const int srow = rbase + m * 16;
        const int b = srow >> 11, s = srow & 2047;
#pragma unroll
        for (int n = 0; n < 4; ++n) {
          const int cg = cbase - 2048 + n * 16;
          const int h = cg >> 6, d = cg & 63;
          ushort4 pk;
          pk.x = f2bf(acc[m][n][0]);
          pk.y = f2bf(acc[m][n][1]);
          pk.z = f2bf(acc[m][n][2]);
          pk.w = f2bf(acc[m][n][3]);
          *(ushort4*)(Vt + ((size_t)(b * 16 + h) * 64 + d) * 2048 + s) = pk;
        }
      }
    }
  }
}

// ---- causal flash attention ----------------------------------------------
// grid (32 q-tiles, 64 bh); 4 waves/block, wave owns 16 q-rows (QBLK=64).
__global__ __launch_bounds__(256)
void attn_kernel(const unsigned short* __restrict__ Qb,
                 const unsigned short* __restrict__ Kb,
                 const unsigned short* __restrict__ Vt,
                 unsigned short* __restrict__ AO) {
  __shared__ unsigned short Ks[64 * 64];      // [k][d]
  __shared__ unsigned short Vs[64 * 64];      // [d][k]  (from Vt)
  __shared__ unsigned short Ps[4][16 * 64];   // per-wave P, rotation-swizzled
  const int tid = threadIdx.x;
  const int lane = tid & 63, wave = tid >> 6;
  const int l16 = lane & 15, g4 = lane >> 4;
  const int qt = blockIdx.x, bh = blockIdx.y;
  const int b = bh >> 4, h = bh & 15;
  const int q0 = qt << 6;

  // Q fragments held in registers for the whole kernel
  const unsigned short* qp =
      Qb + (size_t)(b * 2048 + q0 + wave * 16 + l16) * 1024 + h * 64 + g4 * 8;
  const bf16x8 qf0 = *(const bf16x8*)qp;
  const bf16x8 qf1 = *(const bf16x8*)(qp + 32);

  const f32x4 fz = {0.f, 0.f, 0.f, 0.f};
  f32x4 acc_o[4];
#pragma unroll
  for (int d = 0; d < 4; ++d) acc_o[d] = fz;
  float mrow[4] = {-1e30f, -1e30f, -1e30f, -1e30f};
  float lrow[4] = {0.f, 0.f, 0.f, 0.f};

  const int qrb = q0 + wave * 16 + g4 * 4;    // +r = global q row
  const int pswz_w = g4 << 4;                 // (row&12)<<2 at write (row=g4*4+r)
  const int pswz_r = (l16 & 12) << 2;         // (row&12)<<2 at read  (row=l16)

  for (int kt = 0; kt <= qt; ++kt) {
    __syncthreads();
#pragma unroll
    for (int i = 0; i < 2; ++i) {
      int flat = i * 2048 + tid * 8;
      int r = flat >> 6, c = flat & 63;
      lds_load16(Kb + (size_t)(b * 2048 + kt * 64 + r) * 1024 + h * 64 + c, &Ks[flat]);
      lds_load16(Vt + ((size_t)bh * 64 + r) * 2048 + kt * 64 + c, &Vs[flat]);
    }
    __syncthreads();

    // S = Q K^T  (rows=q, cols=k)
    f32x4 sc[4];
#pragma unroll
    for (int n = 0; n < 4; ++n) {
      f32x4 s = fz;
      s = mfma16(qf0, *(const bf16x8*)&Ks[(n * 16 + l16) * 64 + g4 * 8], s);
      s = mfma16(qf1, *(const bf16x8*)&Ks[(n * 16 + l16) * 64 + 32 + g4 * 8], s);
      sc[n] = s;
    }

    // online softmax, per accumulator row
    float p[4][4];
#pragma unroll
    for (int r = 0; r < 4; ++r) {
      float rm = -1e30f;
#pragma unroll
      for (int n = 0; n < 4; ++n) {
        int kc = kt * 64 + n * 16 + l16;
        float v = (kc <= qrb + r) ? sc[n][r] * 0.125f : -1e30f;
        sc[n][r] = v;
        rm = fmaxf(rm, v);
      }
      rm = fmaxf(rm, __shfl_xor(rm, 1));
      rm = fmaxf(rm, __shfl_xor(rm, 2));
      rm = fmaxf(rm, __shfl_xor(rm, 4));
      rm = fmaxf(rm, __shfl_xor(rm, 8));
      float mn = fmaxf(mrow[r], rm);
      float so = __expf(mrow[r] - mn);
      float sum = 0.f;
#pragma unroll
      for (int n = 0; n < 4; ++n) {
        float pv = __expf(sc[n][r] - mn);
        p[n][r] = pv;
        sum += pv;
      }
      sum += __shfl_xor(sum, 1);
      sum += __shfl_xor(sum, 2);
      sum += __shfl_xor(sum, 4);
      sum += __shfl_xor(sum, 8);
      lrow[r] = lrow[r] * so + sum;
      mrow[r] = mn;
#pragma unroll
      for (int d = 0; d < 4; ++d) acc_o[d][r] *= so;
    }

    // P -> LDS (rotation swizzle: col' = (col + ((row&12)<<2)) & 63)
#pragma unroll
    for (int n = 0; n < 4; ++n) {
      int coff = (n * 16 + l16 + pswz_w) & 63;
#pragma unroll
      for (int r = 0; r < 4; ++r)
        Ps[wave][(g4 * 4 + r) * 64 + coff] = f2bf(p[n][r]);
    }
    bf16x8 pf0 = *(const bf16x8*)&Ps[wave][l16 * 64 + ((g4 * 8 + pswz_r) & 63)];
    bf16x8 pf1 = *(const bf16x8*)&Ps[wave][l16 * 64 + ((32 + g4 * 8 + pswz_r) & 63)];

    // O += P V   (B-operand = Vs[d][k], K-contiguous)
#pragma unroll
    for (int d = 0; d < 4; ++d) {
      acc_o[d] = mfma16(pf0, *(const bf16x8*)&Vs[(d * 16 + l16) * 64 + g4 * 8], acc_o[d]);
      acc_o[d] = mfma16(pf1, *(const bf16x8*)&Vs[(d * 16 + l16) * 64 + 32 + g4 * 8], acc_o[d]);
    }
  }

  const size_t ob = (size_t)(b * 2048 + q0 + wave * 16 + g4 * 4) * 1024 + h * 64 + l16;
#pragma unroll
  for (int r = 0; r < 4; ++r) {
    float inv = 1.f / lrow[r];
#pragma unroll
    for (int d = 0; d < 4; ++d)
      AO[ob + (size_t)r * 1024 + d * 16] = f2bf(acc_o[d][r] * inv);
  }
}

// ---------------------------------------------------------------------------
extern "C" void kernel_launch(void* const* d_in, const int* in_sizes, int n_in,
                              void* d_out, int out_size, void* d_ws, size_t ws_size,
                              hipStream_t stream) {
  const float* x  = (const float*)d_in[0];
  const float* WQ = (const float*)d_in[1];
  const float* WK = (const float*)d_in[2];
  const float* WV = (const float*)d_in[3];
  const float* WO = (const float*)d_in[4];
  float* out = (float*)d_out;

  // workspace layout (bf16 = unsigned short), ~78 MB total
  unsigned short* xb   = (unsigned short*)d_ws;            // [8192][1024]; reused as AO
  unsigned short* wqkv = xb + (size_t)8192 * 1024;         // [3072][1024] WQ|WK|WV
  unsigned short* wo   = wqkv + (size_t)3072 * 1024;       // [1024][1024]
  unsigned short* Qb   = wo + (size_t)1024 * 1024;         // [8192][1024]
  unsigned short* Kb   = Qb + (size_t)8192 * 1024;         // [8192][1024]
  unsigned short* Vt   = Kb + (size_t)8192 * 1024;         // [64 bh][64 d][2048 s]
  float* tab = (float*)(Vt + (size_t)8192 * 1024);         // [2048][32] (cos,sin)

  cast_f32_to_bf16x4<<<8192, 256, 0, stream>>>((const float4*)x, (uint2*)xb, 8192 * 1024 / 4);
  cast_f32_to_bf16x4<<<1024, 256, 0, stream>>>((const float4*)WQ, (uint2*)wqkv, 1024 * 1024 / 4);
  cast_f32_to_bf16x4<<<1024, 256, 0, stream>>>((const float4*)WK, (uint2*)(wqkv + (size_t)1024 * 1024), 1024 * 1024 / 4);
  cast_f32_to_bf16x4<<<1024, 256, 0, stream>>>((const float4*)WV, (uint2*)(wqkv + (size_t)2048 * 1024), 1024 * 1024 / 4);
  cast_f32_to_bf16x4<<<1024, 256, 0, stream>>>((const float4*)WO, (uint2*)wo, 1024 * 1024 / 4);
  rope_table_kernel<<<256, 256, 0, stream>>>(tab);

  // Q|K|V = x @ [WQ|WK|WV]^T   (V lands transposed in Vt)
  gemm_bt<0><<<dim3(24, 64), 256, 0, stream>>>(xb, wqkv, Qb, Kb, Vt, nullptr, 8192, 3072, 1024);

  rope_apply_kernel<<<16384, 256, 0, stream>>>(Qb, (const float2*)tab);
  rope_apply_kernel<<<16384, 256, 0, stream>>>(Kb, (const float2*)tab);

  attn_kernel<<<dim3(32, 64), 256, 0, stream>>>(Qb, Kb, Vt, xb);  // AO aliases xb

  // out = AO @ WO^T  (fp32 out)
  gemm_bt<1><<<dim3(8, 64), 256, 0, stream>>>(xb, wo, nullptr, nullptr, nullptr, out, 8192, 1024, 1024);
}

// Round 3
// 436.038 us; speedup vs baseline: 1.1414x; 1.1414x over previous
//
#include <hip/hip_runtime.h>
#include <stdint.h>

// ---------------------------------------------------------------------------
// MHA w/ RoPE, causal.  B=4 S=2048 D=1024 H=16 dk=64.
// Pipeline: cast->bf16, QKV GEMM (C=A*B^T, V stored transposed), RoPE(Q,K),
// flash attention (online softmax, dbuf + XOR-swizzled LDS), out-proj -> fp32.
// ---------------------------------------------------------------------------

typedef __attribute__((ext_vector_type(8))) __bf16 bf16x8;
typedef __attribute__((ext_vector_type(4))) float f32x4;

typedef __attribute__((address_space(1))) uint32_t AS1u32;
typedef __attribute__((address_space(3))) uint32_t AS3u32;

__device__ __forceinline__ unsigned short f2bf(float f) {
  uint32_t u = __builtin_bit_cast(uint32_t, f);
  u += 0x7fffu + ((u >> 16) & 1u);              // RNE
  return (unsigned short)(u >> 16);
}
__device__ __forceinline__ float bf2f(unsigned short h) {
  return __builtin_bit_cast(float, (uint32_t)h << 16);
}
__device__ __forceinline__ void lds_load16(const void* g, void* l) {
  __builtin_amdgcn_global_load_lds((AS1u32*)g, (AS3u32*)l, 16, 0, 0);
}
__device__ __forceinline__ f32x4 mfma16(bf16x8 a, bf16x8 b, f32x4 c) {
  return __builtin_amdgcn_mfma_f32_16x16x32_bf16(a, b, c, 0, 0, 0);
}

// ---- elementwise ----------------------------------------------------------
__global__ void cast_f32_to_bf16x4(const float4* __restrict__ in,
                                   uint2* __restrict__ out, int n4) {
  int i = blockIdx.x * 256 + threadIdx.x;
  if (i >= n4) return;
  float4 v = in[i];
  uint2 o;
  o.x = (uint32_t)f2bf(v.x) | ((uint32_t)f2bf(v.y) << 16);
  o.y = (uint32_t)f2bf(v.z) | ((uint32_t)f2bf(v.w) << 16);
  out[i] = o;
}

__global__ void rope_table_kernel(float* __restrict__ tab) {
  int i = blockIdx.x * 256 + threadIdx.x;     // 2048*32 exact
  int s = i >> 5, p = i & 31;
  double ang = (double)s * pow(10000.0, -(double)p / 32.0);
  tab[2 * i]     = (float)cos(ang);
  tab[2 * i + 1] = (float)sin(ang);
}

__global__ void rope_apply_kernel(unsigned short* __restrict__ buf,
                                  const float2* __restrict__ tab, float scale) {
  int i = blockIdx.x * 256 + threadIdx.x;     // pair idx, 8192*512 exact
  int row = i >> 9;                           // token row in [0,8192)
  int pp  = i & 511;                          // pair within row
  float2 cs = tab[(row & 2047) * 32 + (pp & 31)];
  uint32_t v = *(uint32_t*)(buf + 2 * (size_t)i);
  float x0 = bf2f((unsigned short)(v & 0xffffu));
  float x1 = bf2f((unsigned short)(v >> 16));
  float o0 = (cs.x * x0 - cs.y * x1) * scale;
  float o1 = (cs.y * x0 + cs.x * x1) * scale;
  *(uint32_t*)(buf + 2 * (size_t)i) =
      (uint32_t)f2bf(o0) | ((uint32_t)f2bf(o1) << 16);
}

// ---- GEMM: C[M][N] = A[M][K] * B[N][K]^T, bf16 in, fp32 acc ---------------
template <int MODE>
__global__ __launch_bounds__(256)
void gemm_bt(const unsigned short* __restrict__ A,
             const unsigned short* __restrict__ B,
             unsigned short* __restrict__ Qo,
             unsigned short* __restrict__ Ko,
             unsigned short* __restrict__ Vt,
             float* __restrict__ CF,
             int M, int N, int K) {
  __shared__ unsigned short As[128 * 64];
  __shared__ unsigned short Bs[128 * 64];
  const int tid = threadIdx.x;
  const int lane = tid & 63, wave = tid >> 6;
  const int l16 = lane & 15, g4 = lane >> 4;
  const int wr = wave >> 1, wc = wave & 1;   // 2x2 waves, 64x64 each
  const int row0 = blockIdx.y * 128;
  const int col0 = blockIdx.x * 128;

  const f32x4 fz = {0.f, 0.f, 0.f, 0.f};
  f32x4 acc[4][4];
#pragma unroll
  for (int m = 0; m < 4; ++m)
#pragma unroll
    for (int n = 0; n < 4; ++n) acc[m][n] = fz;

  for (int kt = 0; kt < K; kt += 64) {
    __syncthreads();
#pragma unroll
    for (int i = 0; i < 4; ++i) {
      int flat = i * 2048 + tid * 8;          // bf16 element index in tile
      int r = flat >> 6, c = flat & 63;
      lds_load16(A + (size_t)(row0 + r) * K + kt + c, &As[flat]);
      lds_load16(B + (size_t)(col0 + r) * K + kt + c, &Bs[flat]);
    }
    __syncthreads();
#pragma unroll
    for (int kk = 0; kk < 2; ++kk) {
      bf16x8 af[4], bfr[4];
#pragma unroll
      for (int m = 0; m < 4; ++m)
        af[m] = *(const bf16x8*)&As[(wr * 64 + m * 16 + l16) * 64 + kk * 32 + g4 * 8];
#pragma unroll
      for (int n = 0; n < 4; ++n)
        bfr[n] = *(const bf16x8*)&Bs[(wc * 64 + n * 16 + l16) * 64 + kk * 32 + g4 * 8];
#pragma unroll
      for (int m = 0; m < 4; ++m)
#pragma unroll
        for (int n = 0; n < 4; ++n)
          acc[m][n] = mfma16(af[m], bfr[n], acc[m][n]);
    }
  }

  // C/D layout: row = g4*4 + r, col = l16  [m89-verified]
  const int rbase = row0 + wr * 64 + g4 * 4;
  const int cbase = col0 + wc * 64 + l16;
  if (MODE == 1) {
#pragma unroll
    for (int m = 0; m < 4; ++m)
#pragma unroll
      for (int n = 0; n < 4; ++n)
#pragma unroll
        for (int r = 0; r < 4; ++r)
          CF[(size_t)(rbase + m * 16 + r) * N + cbase + n * 16] = acc[m][n][r];
  } else {
    const int seg = col0 >> 10;               // 0=Q 1=K 2=V (tiles never straddle)
    if (seg < 2) {
      unsigned short* O = seg ? Ko : Qo;
      const int cl = cbase - (seg << 10);
#pragma unroll
      for (int m = 0; m < 4; ++m)
#pragma unroll
        for (int n = 0; n < 4; ++n)
#pragma unroll
          for (int r = 0; r < 4; ++r)
            O[(size_t)(rbase + m * 16 + r) * 1024 + cl + n * 16] = f2bf(acc[m][n][r]);
    } else {
      // V: write transposed Vt[bh][d][s]; 4 acc rows = 4 consecutive s -> ushort4
#pragma unroll
      for (int m = 0; m < 4; ++m) {
        const int srow = rbase + m * 16;
        const int b = srow >> 11, s = srow & 2047;
#pragma unroll
        for (int n = 0; n < 4; ++n) {
          const int cg = cbase - 2048 + n * 16;
          const int h = cg >> 6, d = cg & 63;
          ushort4 pk;
          pk.x = f2bf(acc[m][n][0]);
          pk.y = f2bf(acc[m][n][1]);
          pk.z = f2bf(acc[m][n][2]);
          pk.w = f2bf(acc[m][n][3]);
          *(ushort4*)(Vt + ((size_t)(b * 16 + h) * 64 + d) * 2048 + s) = pk;
        }
      }
    }
  }
}

// ---- causal flash attention ----------------------------------------------
// grid (32 q-tiles, 64 bh); 4 waves/block, wave owns 16 q-rows (QBLK=64).
// K/V double-buffered in LDS, XOR chunk-swizzle (chunk' = chunk ^ (row&7))
// applied via pre-swizzled global_load_lds SOURCE (LDS dest stays linear).
// Q pre-scaled by 0.125*log2e -> softmax in exp2 domain.
__global__ __launch_bounds__(256)
void attn_kernel(const unsigned short* __restrict__ Qb,
                 const unsigned short* __restrict__ Kb,
                 const unsigned short* __restrict__ Vt,
                 unsigned short* __restrict__ AO) {
  __shared__ unsigned short Ks[2][64 * 64];   // [k][d], swizzled
  __shared__ unsigned short Vs[2][64 * 64];   // [d][k], swizzled
  __shared__ unsigned short Ps[4][16 * 64];   // per-wave P, swizzled
  const int tid = threadIdx.x;
  const int lane = tid & 63, wave = tid >> 6;
  const int l16 = lane & 15, g4 = lane >> 4;
  const int qt = 31 - blockIdx.x;             // longest-first (LPT)
  const int bh = blockIdx.y;
  const int b = bh >> 4, h = bh & 15;
  const int q0 = qt << 6;

  // Q fragments in registers for the whole kernel (pre-scaled by rope pass)
  const unsigned short* qp =
      Qb + (size_t)(b * 2048 + q0 + wave * 16 + l16) * 1024 + h * 64 + g4 * 8;
  const bf16x8 qf0 = *(const bf16x8*)qp;
  const bf16x8 qf1 = *(const bf16x8*)(qp + 32);

  // staging source pointers (pre-swizzled column within each 64x64 tile)
  const unsigned short* kptr[2];
  const unsigned short* vptr[2];
#pragma unroll
  for (int i = 0; i < 2; ++i) {
    int L = i * 256 + tid;                    // 16B chunk index in tile
    int r = L >> 3, ch = L & 7;
    int sc8 = ((ch ^ (r & 7)) << 3);          // pre-swizzled source col
    kptr[i] = Kb + ((size_t)b * 2048 + r) * 1024 + h * 64 + sc8;
    vptr[i] = Vt + ((size_t)bh * 64 + r) * 2048 + sc8;
  }

  const f32x4 fz = {0.f, 0.f, 0.f, 0.f};
  f32x4 acc_o[4];
#pragma unroll
  for (int d = 0; d < 4; ++d) acc_o[d] = fz;
  float mrow[4] = {-1e30f, -1e30f, -1e30f, -1e30f};
  float lrow[4] = {0.f, 0.f, 0.f, 0.f};

  const int qrb = q0 + wave * 16 + g4 * 4;    // +r = global q row
  const int x7 = l16 & 7;
  const int c0 = (g4 ^ x7) << 3;              // swizzled chunk offset, kk=0
  const int pr7 = 4 * (g4 & 1);               // (row&7)-r for P writes

  // prologue: stage tile 0
#pragma unroll
  for (int i = 0; i < 2; ++i) {
    lds_load16(kptr[i], &Ks[0][(i * 256 + tid) * 8]);
    lds_load16(vptr[i], &Vs[0][(i * 256 + tid) * 8]);
  }
  __syncthreads();

  int cur = 0;
  for (int kt = 0; kt <= qt; ++kt) {
    if (kt < qt) {                            // stage next tile into other buf
#pragma unroll
      for (int i = 0; i < 2; ++i) {
        lds_load16(kptr[i] + (size_t)(kt + 1) * 65536, &Ks[cur ^ 1][(i * 256 + tid) * 8]);
        lds_load16(vptr[i] + (size_t)(kt + 1) * 64,    &Vs[cur ^ 1][(i * 256 + tid) * 8]);
      }
    }

    // S = Q K^T  (rows=q, cols=k); K rows read with XOR swizzle
    f32x4 sc[4];
    __builtin_amdgcn_s_setprio(1);
#pragma unroll
    for (int n = 0; n < 4; ++n) {
      f32x4 s = fz;
      s = mfma16(qf0, *(const bf16x8*)&Ks[cur][(n * 16 + l16) * 64 + c0], s);
      s = mfma16(qf1, *(const bf16x8*)&Ks[cur][(n * 16 + l16) * 64 + (c0 ^ 32)], s);
      sc[n] = s;
    }
    __builtin_amdgcn_s_setprio(0);

    if (kt == qt) {                           // causal mask: diagonal tile only
#pragma unroll
      for (int n = 0; n < 4; ++n) {
        int kc = kt * 64 + n * 16 + l16;
#pragma unroll
        for (int r = 0; r < 4; ++r)
          if (kc > qrb + r) sc[n][r] = -1e30f;
      }
    }

    // online softmax (exp2 domain), per accumulator row
    float p[4][4];
#pragma unroll
    for (int r = 0; r < 4; ++r) {
      float rm = fmaxf(fmaxf(sc[0][r], sc[1][r]), fmaxf(sc[2][r], sc[3][r]));
      rm = fmaxf(rm, __shfl_xor(rm, 1));
      rm = fmaxf(rm, __shfl_xor(rm, 2));
      rm = fmaxf(rm, __shfl_xor(rm, 4));
      rm = fmaxf(rm, __shfl_xor(rm, 8));
      float mn = fmaxf(mrow[r], rm);
      float so = __builtin_amdgcn_exp2f(mrow[r] - mn);
      float sum = 0.f;
#pragma unroll
      for (int n = 0; n < 4; ++n) {
        float pv = __builtin_amdgcn_exp2f(sc[n][r] - mn);
        p[n][r] = pv;
        sum += pv;
      }
      sum += __shfl_xor(sum, 1);
      sum += __shfl_xor(sum, 2);
      sum += __shfl_xor(sum, 4);
      sum += __shfl_xor(sum, 8);
      lrow[r] = lrow[r] * so + sum;
      mrow[r] = mn;
#pragma unroll
      for (int d = 0; d < 4; ++d) acc_o[d][r] *= so;
    }

    // P -> LDS with the same XOR chunk-swizzle
#pragma unroll
    for (int n = 0; n < 4; ++n) {
      int chunkbase = 2 * n + (l16 >> 3);
#pragma unroll
      for (int r = 0; r < 4; ++r) {
        int ch = chunkbase ^ (r + pr7);       // ^ (row&7), row = g4*4+r
        Ps[wave][(g4 * 4 + r) * 64 + ch * 8 + x7] = f2bf(p[n][r]);
      }
    }
    bf16x8 pf0 = *(const bf16x8*)&Ps[wave][l16 * 64 + c0];
    bf16x8 pf1 = *(const bf16x8*)&Ps[wave][l16 * 64 + (c0 ^ 32)];

    // O += P V   (B-operand = Vs[d][k], K-contiguous, swizzled)
    __builtin_amdgcn_s_setprio(1);
#pragma unroll
    for (int d = 0; d < 4; ++d) {
      acc_o[d] = mfma16(pf0, *(const bf16x8*)&Vs[cur][(d * 16 + l16) * 64 + c0], acc_o[d]);
      acc_o[d] = mfma16(pf1, *(const bf16x8*)&Vs[cur][(d * 16 + l16) * 64 + (c0 ^ 32)], acc_o[d]);
    }
    __builtin_amdgcn_s_setprio(0);

    __syncthreads();                          // drains vmcnt: next buf ready
    cur ^= 1;
  }

  const size_t ob = (size_t)(b * 2048 + q0 + wave * 16 + g4 * 4) * 1024 + h * 64 + l16;
#pragma unroll
  for (int r = 0; r < 4; ++r) {
    float inv = 1.f / lrow[r];
#pragma unroll
    for (int d = 0; d < 4; ++d)
      AO[ob + (size_t)r * 1024 + d * 16] = f2bf(acc_o[d][r] * inv);
  }
}

// ---------------------------------------------------------------------------
extern "C" void kernel_launch(void* const* d_in, const int* in_sizes, int n_in,
                              void* d_out, int out_size, void* d_ws, size_t ws_size,
                              hipStream_t stream) {
  const float* x  = (const float*)d_in[0];
  const float* WQ = (const float*)d_in[1];
  const float* WK = (const float*)d_in[2];
  const float* WV = (const float*)d_in[3];
  const float* WO = (const float*)d_in[4];
  float* out = (float*)d_out;

  // workspace layout (bf16 = unsigned short), ~78 MB total
  unsigned short* xb   = (unsigned short*)d_ws;            // [8192][1024]; reused as AO
  unsigned short* wqkv = xb + (size_t)8192 * 1024;         // [3072][1024] WQ|WK|WV
  unsigned short* wo   = wqkv + (size_t)3072 * 1024;       // [1024][1024]
  unsigned short* Qb   = wo + (size_t)1024 * 1024;         // [8192][1024]
  unsigned short* Kb   = Qb + (size_t)8192 * 1024;         // [8192][1024]
  unsigned short* Vt   = Kb + (size_t)8192 * 1024;         // [64 bh][64 d][2048 s]
  float* tab = (float*)(Vt + (size_t)8192 * 1024);         // [2048][32] (cos,sin)

  cast_f32_to_bf16x4<<<8192, 256, 0, stream>>>((const float4*)x, (uint2*)xb, 8192 * 1024 / 4);
  cast_f32_to_bf16x4<<<1024, 256, 0, stream>>>((const float4*)WQ, (uint2*)wqkv, 1024 * 1024 / 4);
  cast_f32_to_bf16x4<<<1024, 256, 0, stream>>>((const float4*)WK, (uint2*)(wqkv + (size_t)1024 * 1024), 1024 * 1024 / 4);
  cast_f32_to_bf16x4<<<1024, 256, 0, stream>>>((const float4*)WV, (uint2*)(wqkv + (size_t)2048 * 1024), 1024 * 1024 / 4);
  cast_f32_to_bf16x4<<<1024, 256, 0, stream>>>((const float4*)WO, (uint2*)wo, 1024 * 1024 / 4);
  rope_table_kernel<<<256, 256, 0, stream>>>(tab);

  // Q|K|V = x @ [WQ|WK|WV]^T   (V lands transposed in Vt)
  gemm_bt<0><<<dim3(24, 64), 256, 0, stream>>>(xb, wqkv, Qb, Kb, Vt, nullptr, 8192, 3072, 1024);

  // RoPE; Q additionally pre-scaled by 1/sqrt(dk) * log2(e) for exp2 softmax
  rope_apply_kernel<<<16384, 256, 0, stream>>>(Qb, (const float2*)tab, 0.18033688011112042f);
  rope_apply_kernel<<<16384, 256, 0, stream>>>(Kb, (const float2*)tab, 1.0f);

  attn_kernel<<<dim3(32, 64), 256, 0, stream>>>(Qb, Kb, Vt, xb);  // AO aliases xb

  // out = AO @ WO^T  (fp32 out)
  gemm_bt<1><<<dim3(8, 64), 256, 0, stream>>>(xb, wo, nullptr, nullptr, nullptr, out, 8192, 1024, 1024);
}

// Round 7
// 364.655 us; speedup vs baseline: 1.3648x; 1.1958x over previous
//
#include <hip/hip_runtime.h>
#include <stdint.h>

// ---------------------------------------------------------------------------
// MHA w/ RoPE, causal.  B=4 S=2048 D=1024 H=16 dk=64.
// Pipeline: cast->bf16, QKV GEMM (C=A*B^T, V stored transposed), RoPE(Q,K),
// flash attention (paired q-tiles fold the causal triangle; verified r1
// softmax; dbuf + XOR-swizzled LDS), out-proj -> fp32.
// ---------------------------------------------------------------------------

typedef __attribute__((ext_vector_type(8))) __bf16 bf16x8;
typedef __attribute__((ext_vector_type(4))) float f32x4;

typedef __attribute__((address_space(1))) uint32_t AS1u32;
typedef __attribute__((address_space(3))) uint32_t AS3u32;

__device__ __forceinline__ unsigned short f2bf(float f) {
  uint32_t u = __builtin_bit_cast(uint32_t, f);
  u += 0x7fffu + ((u >> 16) & 1u);              // RNE
  return (unsigned short)(u >> 16);
}
__device__ __forceinline__ float bf2f(unsigned short h) {
  return __builtin_bit_cast(float, (uint32_t)h << 16);
}
__device__ __forceinline__ void lds_load16(const void* g, void* l) {
  __builtin_amdgcn_global_load_lds((AS1u32*)g, (AS3u32*)l, 16, 0, 0);
}
__device__ __forceinline__ f32x4 mfma16(bf16x8 a, bf16x8 b, f32x4 c) {
  return __builtin_amdgcn_mfma_f32_16x16x32_bf16(a, b, c, 0, 0, 0);
}

// ---- elementwise ----------------------------------------------------------
__global__ void cast_f32_to_bf16x4(const float4* __restrict__ in,
                                   uint2* __restrict__ out, int n4) {
  int i = blockIdx.x * 256 + threadIdx.x;
  if (i >= n4) return;
  float4 v = in[i];
  uint2 o;
  o.x = (uint32_t)f2bf(v.x) | ((uint32_t)f2bf(v.y) << 16);
  o.y = (uint32_t)f2bf(v.z) | ((uint32_t)f2bf(v.w) << 16);
  out[i] = o;
}

__global__ void rope_table_kernel(float* __restrict__ tab) {
  int i = blockIdx.x * 256 + threadIdx.x;     // 2048*32 exact
  int s = i >> 5, p = i & 31;
  double ang = (double)s * pow(10000.0, -(double)p / 32.0);
  tab[2 * i]     = (float)cos(ang);
  tab[2 * i + 1] = (float)sin(ang);
}

__global__ void rope_apply_kernel(unsigned short* __restrict__ buf,
                                  const float2* __restrict__ tab, float scale) {
  int i = blockIdx.x * 256 + threadIdx.x;     // pair idx, 8192*512 exact
  int row = i >> 9;                           // token row in [0,8192)
  int pp  = i & 511;                          // pair within row
  float2 cs = tab[(row & 2047) * 32 + (pp & 31)];
  uint32_t v = *(uint32_t*)(buf + 2 * (size_t)i);
  float x0 = bf2f((unsigned short)(v & 0xffffu));
  float x1 = bf2f((unsigned short)(v >> 16));
  float o0 = (cs.x * x0 - cs.y * x1) * scale;
  float o1 = (cs.y * x0 + cs.x * x1) * scale;
  *(uint32_t*)(buf + 2 * (size_t)i) =
      (uint32_t)f2bf(o0) | ((uint32_t)f2bf(o1) << 16);
}

// ---- GEMM: C[M][N] = A[M][K] * B[N][K]^T, bf16 in, fp32 acc ---------------
template <int MODE>
__global__ __launch_bounds__(256)
void gemm_bt(const unsigned short* __restrict__ A,
             const unsigned short* __restrict__ B,
             unsigned short* __restrict__ Qo,
             unsigned short* __restrict__ Ko,
             unsigned short* __restrict__ Vt,
             float* __restrict__ CF,
             int M, int N, int K) {
  __shared__ unsigned short As[128 * 64];
  __shared__ unsigned short Bs[128 * 64];
  const int tid = threadIdx.x;
  const int lane = tid & 63, wave = tid >> 6;
  const int l16 = lane & 15, g4 = lane >> 4;
  const int wr = wave >> 1, wc = wave & 1;   // 2x2 waves, 64x64 each
  const int row0 = blockIdx.y * 128;
  const int col0 = blockIdx.x * 128;

  const f32x4 fz = {0.f, 0.f, 0.f, 0.f};
  f32x4 acc[4][4];
#pragma unroll
  for (int m = 0; m < 4; ++m)
#pragma unroll
    for (int n = 0; n < 4; ++n) acc[m][n] = fz;

  for (int kt = 0; kt < K; kt += 64) {
    __syncthreads();
#pragma unroll
    for (int i = 0; i < 4; ++i) {
      int flat = i * 2048 + tid * 8;          // bf16 element index in tile
      int r = flat >> 6, c = flat & 63;
      lds_load16(A + (size_t)(row0 + r) * K + kt + c, &As[flat]);
      lds_load16(B + (size_t)(col0 + r) * K + kt + c, &Bs[flat]);
    }
    __syncthreads();
#pragma unroll
    for (int kk = 0; kk < 2; ++kk) {
      bf16x8 af[4], bfr[4];
#pragma unroll
      for (int m = 0; m < 4; ++m)
        af[m] = *(const bf16x8*)&As[(wr * 64 + m * 16 + l16) * 64 + kk * 32 + g4 * 8];
#pragma unroll
      for (int n = 0; n < 4; ++n)
        bfr[n] = *(const bf16x8*)&Bs[(wc * 64 + n * 16 + l16) * 64 + kk * 32 + g4 * 8];
#pragma unroll
      for (int m = 0; m < 4; ++m)
#pragma unroll
        for (int n = 0; n < 4; ++n)
          acc[m][n] = mfma16(af[m], bfr[n], acc[m][n]);
    }
  }

  // C/D layout: row = g4*4 + r, col = l16  [m89-verified]
  const int rbase = row0 + wr * 64 + g4 * 4;
  const int cbase = col0 + wc * 64 + l16;
  if (MODE == 1) {
#pragma unroll
    for (int m = 0; m < 4; ++m)
#pragma unroll
      for (int n = 0; n < 4; ++n)
#pragma unroll
        for (int r = 0; r < 4; ++r)
          CF[(size_t)(rbase + m * 16 + r) * N + cbase + n * 16] = acc[m][n][r];
  } else {
    const int seg = col0 >> 10;               // 0=Q 1=K 2=V (tiles never straddle)
    if (seg < 2) {
      unsigned short* O = seg ? Ko : Qo;
      const int cl = cbase - (seg << 10);
#pragma unroll
      for (int m = 0; m < 4; ++m)
#pragma unroll
        for (int n = 0; n < 4; ++n)
#pragma unroll
          for (int r = 0; r < 4; ++r)
            O[(size_t)(rbase + m * 16 + r) * 1024 + cl + n * 16] = f2bf(acc[m][n][r]);
    } else {
      // V: write transposed Vt[bh][d][s]; 4 acc rows = 4 consecutive s -> ushort4
#pragma unroll
      for (int m = 0; m < 4; ++m) {
        const int srow = rbase + m * 16;
        const int b = srow >> 11, s = srow & 2047;
#pragma unroll
        for (int n = 0; n < 4; ++n) {
          const int cg = cbase - 2048 + n * 16;
          const int h = cg >> 6, d = cg & 63;
          ushort4 pk;
          pk.x = f2bf(acc[m][n][0]);
          pk.y = f2bf(acc[m][n][1]);
          pk.z = f2bf(acc[m][n][2]);
          pk.w = f2bf(acc[m][n][3]);
          *(ushort4*)(Vt + ((size_t)(b * 16 + h) * 64 + d) * 2048 + s) = pk;
        }
      }
    }
  }
}

// ---- one q-tile x k-tile attention step (verbatim r1-verified logic) ------
__device__ __forceinline__ void attn_step(
    const unsigned short* Ksb, const unsigned short* Vsb, unsigned short* Psw,
    const bf16x8& q0, const bf16x8& q1, float* mrow, float* lrow,
    f32x4* acc, int qrbase, bool diag, int kt,
    int l16, int g4, int c0, int x7, int pr7) {
  const f32x4 fz = {0.f, 0.f, 0.f, 0.f};

  // S = Q K^T  (rows=q, cols=k); K rows read with XOR swizzle
  f32x4 sc[4];
  __builtin_amdgcn_s_setprio(1);
#pragma unroll
  for (int n = 0; n < 4; ++n) {
    f32x4 s = fz;
    s = mfma16(q0, *(const bf16x8*)&Ksb[(n * 16 + l16) * 64 + c0], s);
    s = mfma16(q1, *(const bf16x8*)&Ksb[(n * 16 + l16) * 64 + (c0 ^ 32)], s);
    sc[n] = s;
  }
  __builtin_amdgcn_s_setprio(0);

  if (diag) {                                 // causal mask: diagonal tile only
#pragma unroll
    for (int n = 0; n < 4; ++n) {
      int kc = kt * 64 + n * 16 + l16;
#pragma unroll
      for (int r = 0; r < 4; ++r)
        if (kc > qrbase + r) sc[n][r] = -1e30f;
    }
  }

  // online softmax (exp2 domain), per accumulator row
  float p[4][4];
#pragma unroll
  for (int r = 0; r < 4; ++r) {
    float rm = fmaxf(fmaxf(sc[0][r], sc[1][r]), fmaxf(sc[2][r], sc[3][r]));
    rm = fmaxf(rm, __shfl_xor(rm, 1));
    rm = fmaxf(rm, __shfl_xor(rm, 2));
    rm = fmaxf(rm, __shfl_xor(rm, 4));
    rm = fmaxf(rm, __shfl_xor(rm, 8));
    float mn = fmaxf(mrow[r], rm);
    float so = __builtin_amdgcn_exp2f(mrow[r] - mn);
    float sum = 0.f;
#pragma unroll
    for (int n = 0; n < 4; ++n) {
      float pv = __builtin_amdgcn_exp2f(sc[n][r] - mn);
      p[n][r] = pv;
      sum += pv;
    }
    sum += __shfl_xor(sum, 1);
    sum += __shfl_xor(sum, 2);
    sum += __shfl_xor(sum, 4);
    sum += __shfl_xor(sum, 8);
    lrow[r] = lrow[r] * so + sum;
    mrow[r] = mn;
#pragma unroll
    for (int d = 0; d < 4; ++d) acc[d][r] *= so;
  }

  // P -> LDS with the same XOR chunk-swizzle
#pragma unroll
  for (int n = 0; n < 4; ++n) {
    int chunkbase = 2 * n + (l16 >> 3);
#pragma unroll
    for (int r = 0; r < 4; ++r) {
      int ch = chunkbase ^ (r + pr7);         // ^ (row&7), row = g4*4+r
      Psw[(g4 * 4 + r) * 64 + ch * 8 + x7] = f2bf(p[n][r]);
    }
  }
  bf16x8 pf0 = *(const bf16x8*)&Psw[l16 * 64 + c0];
  bf16x8 pf1 = *(const bf16x8*)&Psw[l16 * 64 + (c0 ^ 32)];

  // O += P V   (B-operand = Vs[d][k], K-contiguous, swizzled)
  __builtin_amdgcn_s_setprio(1);
#pragma unroll
  for (int d = 0; d < 4; ++d) {
    acc[d] = mfma16(pf0, *(const bf16x8*)&Vsb[(d * 16 + l16) * 64 + c0], acc[d]);
    acc[d] = mfma16(pf1, *(const bf16x8*)&Vsb[(d * 16 + l16) * 64 + (c0 ^ 32)], acc[d]);
  }
  __builtin_amdgcn_s_setprio(0);
}

// ---- causal flash attention, paired q-tiles -------------------------------
// grid (16 qa, 64 bh); block handles q-tiles qa and qb=31-qa -> exactly 33
// tile-computes per block (balanced; each staged K/V tile serves ~1.35
// computes). K/V double-buffered + XOR-swizzled via pre-swizzled
// global_load_lds source. Q pre-scaled by 0.125*log2e (exp2 softmax).
__global__ __launch_bounds__(256)
void attn_kernel(const unsigned short* __restrict__ Qb,
                 const unsigned short* __restrict__ Kb,
                 const unsigned short* __restrict__ Vt,
                 unsigned short* __restrict__ AO) {
  __shared__ unsigned short Ks[2][64 * 64];   // [k][d], swizzled
  __shared__ unsigned short Vs[2][64 * 64];   // [d][k], swizzled
  __shared__ unsigned short Ps[4][16 * 64];   // per-wave P, swizzled
  const int tid = threadIdx.x;
  const int lane = tid & 63, wave = tid >> 6;
  const int l16 = lane & 15, g4 = lane >> 4;
  const int qa = blockIdx.x, qb = 31 - qa;    // qa in [0,16), qb in [16,32)
  const int bh = blockIdx.y;
  const int b = bh >> 4, h = bh & 15;

  // Q fragments for both q-tiles, in registers for the whole kernel
  const unsigned short* qpa =
      Qb + (size_t)(b * 2048 + qa * 64 + wave * 16 + l16) * 1024 + h * 64 + g4 * 8;
  const unsigned short* qpb =
      Qb + (size_t)(b * 2048 + qb * 64 + wave * 16 + l16) * 1024 + h * 64 + g4 * 8;
  const bf16x8 qfa0 = *(const bf16x8*)qpa, qfa1 = *(const bf16x8*)(qpa + 32);
  const bf16x8 qfb0 = *(const bf16x8*)qpb, qfb1 = *(const bf16x8*)(qpb + 32);

  // staging source pointers (pre-swizzled column within each 64x64 tile)
  const unsigned short* kptr[2];
  const unsigned short* vptr[2];
#pragma unroll
  for (int i = 0; i < 2; ++i) {
    int L = i * 256 + tid;                    // 16B chunk index in tile
    int r = L >> 3, ch = L & 7;
    int sc8 = ((ch ^ (r & 7)) << 3);          // pre-swizzled source col
    kptr[i] = Kb + ((size_t)b * 2048 + r) * 1024 + h * 64 + sc8;
    vptr[i] = Vt + ((size_t)bh * 64 + r) * 2048 + sc8;
  }

  const f32x4 fz = {0.f, 0.f, 0.f, 0.f};
  f32x4 acc_a[4], acc_b[4];
#pragma unroll
  for (int d = 0; d < 4; ++d) { acc_a[d] = fz; acc_b[d] = fz; }
  float ma[4], la[4], mb[4], lb[4];
#pragma unroll
  for (int r = 0; r < 4; ++r) {
    ma[r] = -1e30f; mb[r] = -1e30f; la[r] = 0.f; lb[r] = 0.f;
  }

  const int qra  = qa * 64 + wave * 16 + g4 * 4;
  const int qrb_ = qb * 64 + wave * 16 + g4 * 4;
  const int x7 = l16 & 7;
  const int c0 = (g4 ^ x7) << 3;              // swizzled chunk offset, kk=0
  const int pr7 = 4 * (g4 & 1);               // (row&7)-r for P writes

  // prologue: stage tile 0
#pragma unroll
  for (int i = 0; i < 2; ++i) {
    lds_load16(kptr[i], &Ks[0][(i * 256 + tid) * 8]);
    lds_load16(vptr[i], &Vs[0][(i * 256 + tid) * 8]);
  }
  __syncthreads();

  int cur = 0;
  for (int kt = 0; kt <= qb; ++kt) {
    if (kt < qb) {                            // stage next tile into other buf
#pragma unroll
      for (int i = 0; i < 2; ++i) {
        lds_load16(kptr[i] + (size_t)(kt + 1) * 65536, &Ks[cur ^ 1][(i * 256 + tid) * 8]);
        lds_load16(vptr[i] + (size_t)(kt + 1) * 64,    &Vs[cur ^ 1][(i * 256 + tid) * 8]);
      }
    }
    attn_step(Ks[cur], Vs[cur], Ps[wave], qfb0, qfb1, mb, lb, acc_b, qrb_,
              kt == qb, kt, l16, g4, c0, x7, pr7);
    if (kt <= qa)
      attn_step(Ks[cur], Vs[cur], Ps[wave], qfa0, qfa1, ma, la, acc_a, qra,
                kt == qa, kt, l16, g4, c0, x7, pr7);
    __syncthreads();                          // drains vmcnt: next buf ready
    cur ^= 1;
  }

  {
    const size_t ob = (size_t)(b * 2048 + qb * 64 + wave * 16 + g4 * 4) * 1024 + h * 64 + l16;
#pragma unroll
    for (int r = 0; r < 4; ++r) {
      float inv = 1.f / lb[r];
#pragma unroll
      for (int d = 0; d < 4; ++d)
        AO[ob + (size_t)r * 1024 + d * 16] = f2bf(acc_b[d][r] * inv);
    }
  }
  {
    const size_t ob = (size_t)(b * 2048 + qa * 64 + wave * 16 + g4 * 4) * 1024 + h * 64 + l16;
#pragma unroll
    for (int r = 0; r < 4; ++r) {
      float inv = 1.f / la[r];
#pragma unroll
      for (int d = 0; d < 4; ++d)
        AO[ob + (size_t)r * 1024 + d * 16] = f2bf(acc_a[d][r] * inv);
    }
  }
}

// ---------------------------------------------------------------------------
extern "C" void kernel_launch(void* const* d_in, const int* in_sizes, int n_in,
                              void* d_out, int out_size, void* d_ws, size_t ws_size,
                              hipStream_t stream) {
  const float* x  = (const float*)d_in[0];
  const float* WQ = (const float*)d_in[1];
  const float* WK = (const float*)d_in[2];
  const float* WV = (const float*)d_in[3];
  const float* WO = (const float*)d_in[4];
  float* out = (float*)d_out;

  // workspace layout (bf16 = unsigned short), ~78 MB total
  unsigned short* xb   = (unsigned short*)d_ws;            // [8192][1024]; reused as AO
  unsigned short* wqkv = xb + (size_t)8192 * 1024;         // [3072][1024] WQ|WK|WV
  unsigned short* wo   = wqkv + (size_t)3072 * 1024;       // [1024][1024]
  unsigned short* Qb   = wo + (size_t)1024 * 1024;         // [8192][1024]
  unsigned short* Kb   = Qb + (size_t)8192 * 1024;         // [8192][1024]
  unsigned short* Vt   = Kb + (size_t)8192 * 1024;         // [64 bh][64 d][2048 s]
  float* tab = (float*)(Vt + (size_t)8192 * 1024);         // [2048][32] (cos,sin)

  cast_f32_to_bf16x4<<<8192, 256, 0, stream>>>((const float4*)x, (uint2*)xb, 8192 * 1024 / 4);
  cast_f32_to_bf16x4<<<1024, 256, 0, stream>>>((const float4*)WQ, (uint2*)wqkv, 1024 * 1024 / 4);
  cast_f32_to_bf16x4<<<1024, 256, 0, stream>>>((const float4*)WK, (uint2*)(wqkv + (size_t)1024 * 1024), 1024 * 1024 / 4);
  cast_f32_to_bf16x4<<<1024, 256, 0, stream>>>((const float4*)WV, (uint2*)(wqkv + (size_t)2048 * 1024), 1024 * 1024 / 4);
  cast_f32_to_bf16x4<<<1024, 256, 0, stream>>>((const float4*)WO, (uint2*)wo, 1024 * 1024 / 4);
  rope_table_kernel<<<256, 256, 0, stream>>>(tab);

  // Q|K|V = x @ [WQ|WK|WV]^T   (V lands transposed in Vt)
  gemm_bt<0><<<dim3(24, 64), 256, 0, stream>>>(xb, wqkv, Qb, Kb, Vt, nullptr, 8192, 3072, 1024);

  // RoPE; Q additionally pre-scaled by 1/sqrt(dk) * log2(e) for exp2 softmax
  rope_apply_kernel<<<16384, 256, 0, stream>>>(Qb, (const float2*)tab, 0.18033688011112042f);
  rope_apply_kernel<<<16384, 256, 0, stream>>>(Kb, (const float2*)tab, 1.0f);

  attn_kernel<<<dim3(16, 64), 256, 0, stream>>>(Qb, Kb, Vt, xb);  // AO aliases xb

  // out = AO @ WO^T  (fp32 out)
  gemm_bt<1><<<dim3(8, 64), 256, 0, stream>>>(xb, wo, nullptr, nullptr, nullptr, out, 8192, 1024, 1024);
}

// Round 8
// 359.948 us; speedup vs baseline: 1.3826x; 1.0131x over previous
//
#include <hip/hip_runtime.h>
#include <stdint.h>

// ---------------------------------------------------------------------------
// MHA w/ RoPE, causal.  B=4 S=2048 D=1024 H=16 dk=64.
// Pipeline: fused cast->bf16, QKV GEMM (C=A*B^T, V stored transposed),
// RoPE(Q,K) fused launch, flash attention (paired q-tiles; defer-max;
// MFMA-ones row-sum; dbuf + XOR-swizzled LDS), out-proj -> fp32.
// ---------------------------------------------------------------------------

typedef __attribute__((ext_vector_type(8))) __bf16 bf16x8;
typedef __attribute__((ext_vector_type(4))) float f32x4;

typedef __attribute__((address_space(1))) uint32_t AS1u32;
typedef __attribute__((address_space(3))) uint32_t AS3u32;

__device__ __forceinline__ unsigned short f2bf(float f) {
  uint32_t u = __builtin_bit_cast(uint32_t, f);
  u += 0x7fffu + ((u >> 16) & 1u);              // RNE
  return (unsigned short)(u >> 16);
}
__device__ __forceinline__ float bf2f(unsigned short h) {
  return __builtin_bit_cast(float, (uint32_t)h << 16);
}
__device__ __forceinline__ void lds_load16(const void* g, void* l) {
  __builtin_amdgcn_global_load_lds((AS1u32*)g, (AS3u32*)l, 16, 0, 0);
}
__device__ __forceinline__ f32x4 mfma16(bf16x8 a, bf16x8 b, f32x4 c) {
  return __builtin_amdgcn_mfma_f32_16x16x32_bf16(a, b, c, 0, 0, 0);
}

// ---- fused casts (5 regions, one launch) ----------------------------------
__global__ void cast_all_kernel(const float4* __restrict__ x,
                                const float4* __restrict__ wq,
                                const float4* __restrict__ wk,
                                const float4* __restrict__ wv,
                                const float4* __restrict__ wo_in,
                                uint2* __restrict__ xb,
                                uint2* __restrict__ wqkv,
                                uint2* __restrict__ wo_out) {
  const int bid = blockIdx.x;
  const float4* src;
  uint2* dst;
  int idx;
  if (bid < 8192)       { src = x;     dst = xb;             idx = bid * 256 + threadIdx.x; }
  else if (bid < 9216)  { src = wq;    dst = wqkv;           idx = (bid - 8192) * 256 + threadIdx.x; }
  else if (bid < 10240) { src = wk;    dst = wqkv + 262144;  idx = (bid - 9216) * 256 + threadIdx.x; }
  else if (bid < 11264) { src = wv;    dst = wqkv + 524288;  idx = (bid - 10240) * 256 + threadIdx.x; }
  else                  { src = wo_in; dst = wo_out;         idx = (bid - 11264) * 256 + threadIdx.x; }
  float4 v = src[idx];
  uint2 o;
  o.x = (uint32_t)f2bf(v.x) | ((uint32_t)f2bf(v.y) << 16);
  o.y = (uint32_t)f2bf(v.z) | ((uint32_t)f2bf(v.w) << 16);
  dst[idx] = o;
}

__global__ void rope_table_kernel(float* __restrict__ tab) {
  int i = blockIdx.x * 256 + threadIdx.x;     // 2048*32 exact
  int s = i >> 5, p = i & 31;
  double ang = (double)s * pow(10000.0, -(double)p / 32.0);
  tab[2 * i]     = (float)cos(ang);
  tab[2 * i + 1] = (float)sin(ang);
}

// y=0: Q (pre-scaled by 0.125*log2e), y=1: K
__global__ void rope_apply_kernel(unsigned short* __restrict__ Qb,
                                  unsigned short* __restrict__ Kb,
                                  const float2* __restrict__ tab) {
  unsigned short* buf = blockIdx.y ? Kb : Qb;
  const float scale = blockIdx.y ? 1.0f : 0.18033688011112042f;
  int i = blockIdx.x * 256 + threadIdx.x;     // pair idx, 8192*512 exact
  int row = i >> 9;                           // token row in [0,8192)
  int pp  = i & 511;                          // pair within row
  float2 cs = tab[(row & 2047) * 32 + (pp & 31)];
  uint32_t v = *(uint32_t*)(buf + 2 * (size_t)i);
  float x0 = bf2f((unsigned short)(v & 0xffffu));
  float x1 = bf2f((unsigned short)(v >> 16));
  float o0 = (cs.x * x0 - cs.y * x1) * scale;
  float o1 = (cs.y * x0 + cs.x * x1) * scale;
  *(uint32_t*)(buf + 2 * (size_t)i) =
      (uint32_t)f2bf(o0) | ((uint32_t)f2bf(o1) << 16);
}

// ---- GEMM: C[M][N] = A[M][K] * B[N][K]^T, bf16 in, fp32 acc ---------------
template <int MODE>
__global__ __launch_bounds__(256)
void gemm_bt(const unsigned short* __restrict__ A,
             const unsigned short* __restrict__ B,
             unsigned short* __restrict__ Qo,
             unsigned short* __restrict__ Ko,
             unsigned short* __restrict__ Vt,
             float* __restrict__ CF,
             int M, int N, int K) {
  __shared__ unsigned short As[128 * 64];
  __shared__ unsigned short Bs[128 * 64];
  const int tid = threadIdx.x;
  const int lane = tid & 63, wave = tid >> 6;
  const int l16 = lane & 15, g4 = lane >> 4;
  const int wr = wave >> 1, wc = wave & 1;   // 2x2 waves, 64x64 each
  const int row0 = blockIdx.y * 128;
  const int col0 = blockIdx.x * 128;

  const f32x4 fz = {0.f, 0.f, 0.f, 0.f};
  f32x4 acc[4][4];
#pragma unroll
  for (int m = 0; m < 4; ++m)
#pragma unroll
    for (int n = 0; n < 4; ++n) acc[m][n] = fz;

  for (int kt = 0; kt < K; kt += 64) {
    __syncthreads();
#pragma unroll
    for (int i = 0; i < 4; ++i) {
      int flat = i * 2048 + tid * 8;          // bf16 element index in tile
      int r = flat >> 6, c = flat & 63;
      lds_load16(A + (size_t)(row0 + r) * K + kt + c, &As[flat]);
      lds_load16(B + (size_t)(col0 + r) * K + kt + c, &Bs[flat]);
    }
    __syncthreads();
#pragma unroll
    for (int kk = 0; kk < 2; ++kk) {
      bf16x8 af[4], bfr[4];
#pragma unroll
      for (int m = 0; m < 4; ++m)
        af[m] = *(const bf16x8*)&As[(wr * 64 + m * 16 + l16) * 64 + kk * 32 + g4 * 8];
#pragma unroll
      for (int n = 0; n < 4; ++n)
        bfr[n] = *(const bf16x8*)&Bs[(wc * 64 + n * 16 + l16) * 64 + kk * 32 + g4 * 8];
#pragma unroll
      for (int m = 0; m < 4; ++m)
#pragma unroll
        for (int n = 0; n < 4; ++n)
          acc[m][n] = mfma16(af[m], bfr[n], acc[m][n]);
    }
  }

  // C/D layout: row = g4*4 + r, col = l16  [m89-verified]
  const int rbase = row0 + wr * 64 + g4 * 4;
  const int cbase = col0 + wc * 64 + l16;
  if (MODE == 1) {
#pragma unroll
    for (int m = 0; m < 4; ++m)
#pragma unroll
      for (int n = 0; n < 4; ++n)
#pragma unroll
        for (int r = 0; r < 4; ++r)
          CF[(size_t)(rbase + m * 16 + r) * N + cbase + n * 16] = acc[m][n][r];
  } else {
    const int seg = col0 >> 10;               // 0=Q 1=K 2=V (tiles never straddle)
    if (seg < 2) {
      unsigned short* O = seg ? Ko : Qo;
      const int cl = cbase - (seg << 10);
#pragma unroll
      for (int m = 0; m < 4; ++m)
#pragma unroll
        for (int n = 0; n < 4; ++n)
#pragma unroll
          for (int r = 0; r < 4; ++r)
            O[(size_t)(rbase + m * 16 + r) * 1024 + cl + n * 16] = f2bf(acc[m][n][r]);
    } else {
      // V: write transposed Vt[bh][d][s]; 4 acc rows = 4 consecutive s -> ushort4
#pragma unroll
      for (int m = 0; m < 4; ++m) {
        const int srow = rbase + m * 16;
        const int b = srow >> 11, s = srow & 2047;
#pragma unroll
        for (int n = 0; n < 4; ++n) {
          const int cg = cbase - 2048 + n * 16;
          const int h = cg >> 6, d = cg & 63;
          ushort4 pk;
          pk.x = f2bf(acc[m][n][0]);
          pk.y = f2bf(acc[m][n][1]);
          pk.z = f2bf(acc[m][n][2]);
          pk.w = f2bf(acc[m][n][3]);
          *(ushort4*)(Vt + ((size_t)(b * 16 + h) * 64 + d) * 2048 + s) = pk;
        }
      }
    }
  }
}

// ---- one q-tile x k-tile attention step -----------------------------------
// r7-verified structure + (a) defer-max rescale (THR=8, wave-uniform) and
// (b) row-sum via MFMA-with-ones (denominator from the same bf16 P as PV).
__device__ __forceinline__ void attn_step(
    const unsigned short* Ksb, const unsigned short* Vsb, unsigned short* Psw,
    const bf16x8& q0, const bf16x8& q1, float* mrow, f32x4& acc_l,
    f32x4* acc, const bf16x8& ones8, int qrbase, bool diag, int kt,
    int l16, int g4, int c0, int x7, int pr7) {
  const f32x4 fz = {0.f, 0.f, 0.f, 0.f};

  // S = Q K^T  (rows=q, cols=k); K rows read with XOR swizzle
  f32x4 sc[4];
  __builtin_amdgcn_s_setprio(1);
#pragma unroll
  for (int n = 0; n < 4; ++n) {
    f32x4 s = fz;
    s = mfma16(q0, *(const bf16x8*)&Ksb[(n * 16 + l16) * 64 + c0], s);
    s = mfma16(q1, *(const bf16x8*)&Ksb[(n * 16 + l16) * 64 + (c0 ^ 32)], s);
    sc[n] = s;
  }
  __builtin_amdgcn_s_setprio(0);

  if (diag) {                                 // causal mask: diagonal tile only
#pragma unroll
    for (int n = 0; n < 4; ++n) {
      int kc = kt * 64 + n * 16 + l16;
#pragma unroll
      for (int r = 0; r < 4; ++r)
        if (kc > qrbase + r) sc[n][r] = -1e30f;
    }
  }

  // online softmax (exp2 domain), defer-max: rescale only when max grew >8
  float p[4][4];
#pragma unroll
  for (int r = 0; r < 4; ++r) {
    float rm = fmaxf(fmaxf(sc[0][r], sc[1][r]), fmaxf(sc[2][r], sc[3][r]));
    rm = fmaxf(rm, __shfl_xor(rm, 1));
    rm = fmaxf(rm, __shfl_xor(rm, 2));
    rm = fmaxf(rm, __shfl_xor(rm, 4));
    rm = fmaxf(rm, __shfl_xor(rm, 8));
    if (!__all(rm <= mrow[r] + 8.f)) {        // P stays bounded by 2^8
      float mn = fmaxf(mrow[r], rm);
      float so = __builtin_amdgcn_exp2f(mrow[r] - mn);
      acc_l[r] *= so;
#pragma unroll
      for (int d = 0; d < 4; ++d) acc[d][r] *= so;
      mrow[r] = mn;
    }
#pragma unroll
    for (int n = 0; n < 4; ++n)
      p[n][r] = __builtin_amdgcn_exp2f(sc[n][r] - mrow[r]);
  }

  // P -> LDS with the same XOR chunk-swizzle
#pragma unroll
  for (int n = 0; n < 4; ++n) {
    int chunkbase = 2 * n + (l16 >> 3);
#pragma unroll
    for (int r = 0; r < 4; ++r) {
      int ch = chunkbase ^ (r + pr7);         // ^ (row&7), row = g4*4+r
      Psw[(g4 * 4 + r) * 64 + ch * 8 + x7] = f2bf(p[n][r]);
    }
  }
  bf16x8 pf0 = *(const bf16x8*)&Psw[l16 * 64 + c0];
  bf16x8 pf1 = *(const bf16x8*)&Psw[l16 * 64 + (c0 ^ 32)];

  // lrow += P*1 and O += P V on the matrix pipe
  __builtin_amdgcn_s_setprio(1);
  acc_l = mfma16(pf0, ones8, acc_l);
  acc_l = mfma16(pf1, ones8, acc_l);
#pragma unroll
  for (int d = 0; d < 4; ++d) {
    acc[d] = mfma16(pf0, *(const bf16x8*)&Vsb[(d * 16 + l16) * 64 + c0], acc[d]);
    acc[d] = mfma16(pf1, *(const bf16x8*)&Vsb[(d * 16 + l16) * 64 + (c0 ^ 32)], acc[d]);
  }
  __builtin_amdgcn_s_setprio(0);
}

// ---- causal flash attention, paired q-tiles -------------------------------
// grid (16 qa, 64 bh); block handles q-tiles qa and qb=31-qa -> exactly 33
// tile-computes per block (balanced). K/V double-buffered + XOR-swizzled via
// pre-swizzled global_load_lds source. Q pre-scaled by 0.125*log2e.
__global__ __launch_bounds__(256)
void attn_kernel(const unsigned short* __restrict__ Qb,
                 const unsigned short* __restrict__ Kb,
                 const unsigned short* __restrict__ Vt,
                 unsigned short* __restrict__ AO) {
  __shared__ unsigned short Ks[2][64 * 64];   // [k][d], swizzled
  __shared__ unsigned short Vs[2][64 * 64];   // [d][k], swizzled
  __shared__ unsigned short Ps[4][16 * 64];   // per-wave P, swizzled
  const int tid = threadIdx.x;
  const int lane = tid & 63, wave = tid >> 6;
  const int l16 = lane & 15, g4 = lane >> 4;
  const int qa = blockIdx.x, qb = 31 - qa;    // qa in [0,16), qb in [16,32)
  const int bh = blockIdx.y;
  const int b = bh >> 4, h = bh & 15;

  // Q fragments for both q-tiles, in registers for the whole kernel
  const unsigned short* qpa =
      Qb + (size_t)(b * 2048 + qa * 64 + wave * 16 + l16) * 1024 + h * 64 + g4 * 8;
  const unsigned short* qpb =
      Qb + (size_t)(b * 2048 + qb * 64 + wave * 16 + l16) * 1024 + h * 64 + g4 * 8;
  const bf16x8 qfa0 = *(const bf16x8*)qpa, qfa1 = *(const bf16x8*)(qpa + 32);
  const bf16x8 qfb0 = *(const bf16x8*)qpb, qfb1 = *(const bf16x8*)(qpb + 32);

  // staging source pointers (pre-swizzled column within each 64x64 tile)
  const unsigned short* kptr[2];
  const unsigned short* vptr[2];
#pragma unroll
  for (int i = 0; i < 2; ++i) {
    int L = i * 256 + tid;                    // 16B chunk index in tile
    int r = L >> 3, ch = L & 7;
    int sc8 = ((ch ^ (r & 7)) << 3);          // pre-swizzled source col
    kptr[i] = Kb + ((size_t)b * 2048 + r) * 1024 + h * 64 + sc8;
    vptr[i] = Vt + ((size_t)bh * 64 + r) * 2048 + sc8;
  }

  const f32x4 fz = {0.f, 0.f, 0.f, 0.f};
  f32x4 acc_a[4], acc_b[4], acc_la = fz, acc_lb = fz;
#pragma unroll
  for (int d = 0; d < 4; ++d) { acc_a[d] = fz; acc_b[d] = fz; }
  float ma[4], mb[4];
#pragma unroll
  for (int r = 0; r < 4; ++r) { ma[r] = -1e30f; mb[r] = -1e30f; }

  const int qra  = qa * 64 + wave * 16 + g4 * 4;
  const int qrb_ = qb * 64 + wave * 16 + g4 * 4;
  const int x7 = l16 & 7;
  const int c0 = (g4 ^ x7) << 3;              // swizzled chunk offset, kk=0
  const int pr7 = 4 * (g4 & 1);               // (row&7)-r for P writes

  bf16x8 ones8;
#pragma unroll
  for (int j = 0; j < 8; ++j) ones8[j] = (__bf16)1.0f;

  // prologue: stage tile 0
#pragma unroll
  for (int i = 0; i < 2; ++i) {
    lds_load16(kptr[i], &Ks[0][(i * 256 + tid) * 8]);
    lds_load16(vptr[i], &Vs[0][(i * 256 + tid) * 8]);
  }
  __syncthreads();

  int cur = 0;
  for (int kt = 0; kt <= qb; ++kt) {
    if (kt < qb) {                            // stage next tile into other buf
#pragma unroll
      for (int i = 0; i < 2; ++i) {
        lds_load16(kptr[i] + (size_t)(kt + 1) * 65536, &Ks[cur ^ 1][(i * 256 + tid) * 8]);
        lds_load16(vptr[i] + (size_t)(kt + 1) * 64,    &Vs[cur ^ 1][(i * 256 + tid) * 8]);
      }
    }
    attn_step(Ks[cur], Vs[cur], Ps[wave], qfb0, qfb1, mb, acc_lb, acc_b, ones8,
              qrb_, kt == qb, kt, l16, g4, c0, x7, pr7);
    if (kt <= qa)
      attn_step(Ks[cur], Vs[cur], Ps[wave], qfa0, qfa1, ma, acc_la, acc_a, ones8,
                qra, kt == qa, kt, l16, g4, c0, x7, pr7);
    __syncthreads();                          // drains vmcnt: next buf ready
    cur ^= 1;
  }

  {
    const size_t ob = (size_t)(b * 2048 + qb * 64 + wave * 16 + g4 * 4) * 1024 + h * 64 + l16;
#pragma unroll
    for (int r = 0; r < 4; ++r) {
      float inv = 1.f / acc_lb[r];
#pragma unroll
      for (int d = 0; d < 4; ++d)
        AO[ob + (size_t)r * 1024 + d * 16] = f2bf(acc_b[d][r] * inv);
    }
  }
  {
    const size_t ob = (size_t)(b * 2048 + qa * 64 + wave * 16 + g4 * 4) * 1024 + h * 64 + l16;
#pragma unroll
    for (int r = 0; r < 4; ++r) {
      float inv = 1.f / acc_la[r];
#pragma unroll
      for (int d = 0; d < 4; ++d)
        AO[ob + (size_t)r * 1024 + d * 16] = f2bf(acc_a[d][r] * inv);
    }
  }
}

// ---------------------------------------------------------------------------
extern "C" void kernel_launch(void* const* d_in, const int* in_sizes, int n_in,
                              void* d_out, int out_size, void* d_ws, size_t ws_size,
                              hipStream_t stream) {
  const float* x  = (const float*)d_in[0];
  const float* WQ = (const float*)d_in[1];
  const float* WK = (const float*)d_in[2];
  const float* WV = (const float*)d_in[3];
  const float* WO = (const float*)d_in[4];
  float* out = (float*)d_out;

  // workspace layout (bf16 = unsigned short), ~78 MB total
  unsigned short* xb   = (unsigned short*)d_ws;            // [8192][1024]; reused as AO
  unsigned short* wqkv = xb + (size_t)8192 * 1024;         // [3072][1024] WQ|WK|WV
  unsigned short* wo   = wqkv + (size_t)3072 * 1024;       // [1024][1024]
  unsigned short* Qb   = wo + (size_t)1024 * 1024;         // [8192][1024]
  unsigned short* Kb   = Qb + (size_t)8192 * 1024;         // [8192][1024]
  unsigned short* Vt   = Kb + (size_t)8192 * 1024;         // [64 bh][64 d][2048 s]
  float* tab = (float*)(Vt + (size_t)8192 * 1024);         // [2048][32] (cos,sin)

  cast_all_kernel<<<12288, 256, 0, stream>>>(
      (const float4*)x, (const float4*)WQ, (const float4*)WK,
      (const float4*)WV, (const float4*)WO,
      (uint2*)xb, (uint2*)wqkv, (uint2*)wo);
  rope_table_kernel<<<256, 256, 0, stream>>>(tab);

  // Q|K|V = x @ [WQ|WK|WV]^T   (V lands transposed in Vt)
  gemm_bt<0><<<dim3(24, 64), 256, 0, stream>>>(xb, wqkv, Qb, Kb, Vt, nullptr, 8192, 3072, 1024);

  // RoPE both Q (pre-scaled by 0.125*log2e) and K in one launch
  rope_apply_kernel<<<dim3(16384, 2), 256, 0, stream>>>(Qb, Kb, (const float2*)tab);

  attn_kernel<<<dim3(16, 64), 256, 0, stream>>>(Qb, Kb, Vt, xb);  // AO aliases xb

  // out = AO @ WO^T  (fp32 out)
  gemm_bt<1><<<dim3(8, 64), 256, 0, stream>>>(xb, wo, nullptr, nullptr, nullptr, out, 8192, 1024, 1024);
}